// Round 5
// baseline (808.011 us; speedup 1.0000x reference)
//
#include <hip/hip_runtime.h>
#include <math.h>

#define BB 16
#define LL 4096
#define HH 128
#define NN2 32
#define NHALF 16
#define CHUNK 128
#define NCHUNK 32
#define NLAYERS 4
#define DOUTN 100
#define TWOH 256

typedef __attribute__((ext_vector_type(8))) short short8;
typedef __attribute__((ext_vector_type(4))) float f32x4;

__device__ __forceinline__ unsigned short f2bf(float f) {
    unsigned int u = __builtin_bit_cast(unsigned int, f);
    unsigned int r = (u + 0x7FFFu + ((u >> 16) & 1u)) >> 16;
    return (unsigned short)r;
}
__device__ __forceinline__ float bf2f(unsigned short s) {
    unsigned int u = ((unsigned int)s) << 16;
    return __builtin_bit_cast(float, u);
}

// ---------------- pack out_w (nl,2H,H) into MFMA A-fragment layout, bf16 hi/lo ----------------
// A-frag for mfma_f32_16x16x32_bf16: lane = m + 16*(k/8), elem = k%8.
// Apack[(layer*16+ot)*4+ks][lane][8] ; m = lane&15 -> o = ot*16+m ; k = ks*32+(lane>>4)*8+e -> h.
__global__ __launch_bounds__(256) void k_pack(const float* __restrict__ out_w,
                                              short* __restrict__ Ahi, short* __restrict__ Alo) {
    int idx = blockIdx.x * 256 + threadIdx.x;          // 4*16*4*64 = 16384
    if (idx >= NLAYERS * 16 * 4 * 64) return;
    int lane = idx & 63;
    int ks   = (idx >> 6) & 3;
    int ot   = (idx >> 8) & 15;
    int layer = idx >> 12;
    int o = ot * 16 + (lane & 15);
    short8 hi, lo;
#pragma unroll
    for (int e = 0; e < 8; ++e) {
        int h = ks * 32 + (lane >> 4) * 8 + e;
        float w = out_w[((size_t)(layer * TWOH + o)) * HH + h];
        unsigned short wh = f2bf(w);
        float res = w - bf2f(wh);
        hi[e] = (short)wh;
        lo[e] = (short)f2bf(res);
    }
    *(short8*)(Ahi + (size_t)idx * 8) = hi;
    *(short8*)(Alo + (size_t)idx * 8) = lo;
}

// ---------------- encoder: h[b,h,l] = x[b,l]*enc_w[h] + enc_b[h] ----------------
__global__ __launch_bounds__(256) void k_enc(const float* __restrict__ x, const float* __restrict__ enc_w,
                                             const float* __restrict__ enc_b, float* __restrict__ hbuf) {
    int idx = blockIdx.x * 256 + threadIdx.x;       // over B*H*L/4
    int l4 = idx & (LL / 4 - 1);
    int h  = (idx / (LL / 4)) & (HH - 1);
    int b  = idx / (LL / 4 * HH);
    float4 xv = ((const float4*)(x + (size_t)b * LL))[l4];
    float w = enc_w[h], bb = enc_b[h];
    float4 o;
    o.x = fmaf(xv.x, w, bb);
    o.y = fmaf(xv.y, w, bb);
    o.z = fmaf(xv.z, w, bb);
    o.w = fmaf(xv.w, w, bb);
    ((float4*)(hbuf + ((size_t)b * HH + h) * LL))[l4] = o;
}

// ---------------- SSM scan, chunk-parallel, 16 modes/lane (unchanged from R4) ----------------
__global__ __launch_bounds__(64, 2) void k_scan(const float* __restrict__ u_, float* __restrict__ y_,
                                                const float* __restrict__ log_dt, const float* __restrict__ Cc,
                                                const float* __restrict__ log_A_real, const float* __restrict__ A_imag,
                                                int layer) {
    int row   = blockIdx.x;                 // b*H + h
    int h     = row & (HH - 1);
    int lane  = threadIdx.x;
    int chunk = lane & 31;
    int half  = lane >> 5;
    const float* urow = u_ + (size_t)row * LL + chunk * CHUNK;
    float*       yrow = y_ + (size_t)row * LL + chunk * CHUNK;

    float dt = expf(log_dt[layer * HH + h]);
    float plr[NHALF], pli[NHALF], pc2r[NHALF], pc2i[NHALF], pmr[NHALF], pmi[NHALF];
#pragma unroll
    for (int n = 0; n < NHALF; ++n) {
        int pidx = (layer * HH + h) * NN2 + half * NHALF + n;
        float Ar  = -expf(log_A_real[pidx]);
        float Ai  = A_imag[pidx];
        float dAr = Ar * dt, dAi = Ai * dt;
        float el  = expf(dAr);
        float lr  = el * cosf(dAi);
        float li  = el * sinf(dAi);
        plr[n] = lr; pli[n] = li;
        float nr  = lr - 1.0f, ni = li;
        float inv = 1.0f / (Ar * Ar + Ai * Ai);
        float gr  = (nr * Ar + ni * Ai) * inv;
        float gi  = (ni * Ar - nr * Ai) * inv;
        float Cre = Cc[pidx * 2], Cim = Cc[pidx * 2 + 1];
        pc2r[n] = 2.0f * (Cre * gr - Cim * gi);
        pc2i[n] = 2.0f * (Cre * gi + Cim * gr);
        float eC = expf(dAr * (float)CHUNK);
        float aC = dAi * (float)CHUNK;
        pmr[n] = eC * cosf(aC);
        pmi[n] = eC * sinf(aC);
    }

    float sr[NHALF], si[NHALF];
#pragma unroll
    for (int n = 0; n < NHALF; ++n) { sr[n] = 0.0f; si[n] = 0.0f; }

    // phase 1: local chunk scan (zero init)
    float4 uv = *(const float4*)(urow);
#pragma unroll 1
    for (int s0 = 0; s0 < CHUNK; s0 += 4) {
        int sn = s0 + 4 < CHUNK ? s0 + 4 : CHUNK - 4;
        float4 uvn = *(const float4*)(urow + sn);
        float us4[4] = {uv.x, uv.y, uv.z, uv.w};
#pragma unroll
        for (int j = 0; j < 4; ++j) {
            float u = us4[j];
#pragma unroll
            for (int n = 0; n < NHALF; ++n) {
                float t   = fmaf(-pli[n], si[n], u);
                float nsi = fmaf(pli[n], sr[n], plr[n] * si[n]);
                sr[n] = fmaf(plr[n], sr[n], t);
                si[n] = nsi;
            }
        }
        uv = uvn;
    }

    // combine: inclusive complex prefix over 32 chunks (per half)
    {
        float mr[NHALF], mi[NHALF];
#pragma unroll
        for (int n = 0; n < NHALF; ++n) { mr[n] = pmr[n]; mi[n] = pmi[n]; }
#pragma unroll
        for (int k = 1; k < NCHUNK; k <<= 1) {
#pragma unroll
            for (int n = 0; n < NHALF; ++n) {
                float vr = __shfl_up(sr[n], k);
                float vi = __shfl_up(si[n], k);
                vr = (chunk >= k) ? vr : 0.0f;
                vi = (chunk >= k) ? vi : 0.0f;
                sr[n] = fmaf(mr[n], vr, fmaf(-mi[n], vi, sr[n]));
                si[n] = fmaf(mr[n], vi, fmaf(mi[n], vr, si[n]));
            }
#pragma unroll
            for (int n = 0; n < NHALF; ++n) {
                float t = fmaf(mr[n], mr[n], -(mi[n] * mi[n]));
                mi[n] = 2.0f * mr[n] * mi[n];
                mr[n] = t;
            }
        }
#pragma unroll
        for (int n = 0; n < NHALF; ++n) {
            float vr = __shfl_up(sr[n], 1);
            float vi = __shfl_up(si[n], 1);
            sr[n] = (chunk >= 1) ? vr : 0.0f;
            si[n] = (chunk >= 1) ? vi : 0.0f;
        }
    }

    // phase 2: re-run with true incoming state, emit y
    uv = *(const float4*)(urow);
#pragma unroll 1
    for (int s0 = 0; s0 < CHUNK; s0 += 4) {
        int sn = s0 + 4 < CHUNK ? s0 + 4 : CHUNK - 4;
        float4 uvn = *(const float4*)(urow + sn);
        float us4[4] = {uv.x, uv.y, uv.z, uv.w};
        float out4[4];
#pragma unroll
        for (int j = 0; j < 4; ++j) {
            float u = us4[j];
            float acc_a = 0.0f, acc_b = 0.0f;
#pragma unroll
            for (int n = 0; n < NHALF; n += 2) {
                {
                    float t   = fmaf(-pli[n], si[n], u);
                    float nsi = fmaf(pli[n], sr[n], plr[n] * si[n]);
                    sr[n] = fmaf(plr[n], sr[n], t);
                    si[n] = nsi;
                    acc_a = fmaf(pc2r[n], sr[n], fmaf(-pc2i[n], si[n], acc_a));
                }
                {
                    int m = n + 1;
                    float t   = fmaf(-pli[m], si[m], u);
                    float nsi = fmaf(pli[m], sr[m], plr[m] * si[m]);
                    sr[m] = fmaf(plr[m], sr[m], t);
                    si[m] = nsi;
                    acc_b = fmaf(pc2r[m], sr[m], fmaf(-pc2i[m], si[m], acc_b));
                }
            }
            out4[j] = acc_a + acc_b;
        }
        out4[0] += __shfl_xor(out4[0], 32);
        out4[1] += __shfl_xor(out4[1], 32);
        out4[2] += __shfl_xor(out4[2], 32);
        out4[3] += __shfl_xor(out4[3], 32);
        if (half == 0) *(float4*)(yrow + s0) = make_float4(out4[0], out4[1], out4[2], out4[3]);
        uv = uvn;
    }
}

// ---------------- conv(1x1 H->2H) via MFMA bf16 hi/lo + GLU + residual + LayerNorm ----------------
// Block = (b, 64-l tile). gelu(y + D*u) staged transposed in LDS as bf16 hi/lo:
// gT[l][h], h contiguous, 16B-granule XOR swizzle (granule ^= l&7). 4 waves;
// wave w owns l-window [w*16, w*16+16), all 16 o-tiles. 3 MFMA passes
// (Whi*ghi + Whi*glo + Wlo*ghi) give fp32-level accuracy.
__global__ __launch_bounds__(256, 3) void k_conv(float* __restrict__ hbuf, const float* __restrict__ ybuf,
                                                 const short* __restrict__ Ahi, const short* __restrict__ Alo,
                                                 const float* __restrict__ out_b, const float* __restrict__ Dp,
                                                 const float* __restrict__ ln_g, const float* __restrict__ ln_b,
                                                 int layer) {
    __shared__ short ghi[64 * 16 * 8];    // [l][granule(^swz)][8 bf16] = 16 KB
    __shared__ short glo[64 * 16 * 8];
    int tid = threadIdx.x;
    int blk = blockIdx.x;                 // B * (L/64)
    int b   = blk >> 6;
    int l0  = (blk & 63) << 6;
    const float* Drow = Dp + layer * HH;

    // ---- staging: thread t -> l = t&63, q = t>>6 ; covers h-octet (iter*4+q) ----
    {
        int l = tid & 63;
        int q = tid >> 6;
#pragma unroll
        for (int iter = 0; iter < 4; ++iter) {
            int oct = iter * 4 + q;           // h-octet 0..15
            short8 hi8, lo8;
#pragma unroll
            for (int i = 0; i < 8; ++i) {
                int h = oct * 8 + i;
                size_t base = ((size_t)(b * HH + h)) * LL + l0 + l;
                float yv = ybuf[base];
                float uvv = hbuf[base];
                float t = fmaf(Drow[h], uvv, yv);
                float g = 0.5f * t * (1.0f + erff(t * 0.70710678118654752f));
                unsigned short gh = f2bf(g);
                hi8[i] = (short)gh;
                lo8[i] = (short)f2bf(g - bf2f(gh));
            }
            int phys = (l * 16 + (oct ^ (l & 7))) * 8;
            *(short8*)(ghi + phys) = hi8;
            *(short8*)(glo + phys) = lo8;
        }
    }
    __syncthreads();

    // ---- MFMA: wave = tid>>6 owns l-window, lane-> (n = lane&15, kg = lane>>4) ----
    int wave = tid >> 6;
    int lane = tid & 63;
    int n    = lane & 15;
    int kg   = lane >> 4;
    int ll   = wave * 16 + n;             // local l of this lane's B column / D column

    short8 Bhi[4], Blo[4];
#pragma unroll
    for (int ks = 0; ks < 4; ++ks) {
        int phys = (ll * 16 + ((ks * 4 + kg) ^ (ll & 7))) * 8;
        Bhi[ks] = *(const short8*)(ghi + phys);
        Blo[ks] = *(const short8*)(glo + phys);
    }

    f32x4 acc[16];
#pragma unroll
    for (int ot = 0; ot < 16; ++ot) acc[ot] = (f32x4)(0.0f);

    const short* Abase_hi = Ahi + ((size_t)(layer * 16) * 4 * 64) * 8;
    const short* Abase_lo = Alo + ((size_t)(layer * 16) * 4 * 64) * 8;
#pragma unroll
    for (int ot = 0; ot < 16; ++ot) {
#pragma unroll
        for (int ks = 0; ks < 4; ++ks) {
            size_t aoff = ((size_t)(ot * 4 + ks) * 64 + lane) * 8;
            short8 ah = *(const short8*)(Abase_hi + aoff);
            short8 al = *(const short8*)(Abase_lo + aoff);
            acc[ot] = __builtin_amdgcn_mfma_f32_16x16x32_bf16(ah, Bhi[ks], acc[ot], 0, 0, 0);
            acc[ot] = __builtin_amdgcn_mfma_f32_16x16x32_bf16(ah, Blo[ks], acc[ot], 0, 0, 0);
            acc[ot] = __builtin_amdgcn_mfma_f32_16x16x32_bf16(al, Bhi[ks], acc[ot], 0, 0, 0);
        }
    }

    // ---- epilogue: bias + GLU + residual, then LN over 128 ch (lanes n,n+16,n+32,n+48) ----
    size_t lpos = (size_t)l0 + wave * 16 + n;
    const float* obL = out_b + layer * TWOH;
    float s = 0.0f, qq = 0.0f;
#pragma unroll
    for (int ot = 0; ot < 8; ++ot) {
#pragma unroll
        for (int e = 0; e < 4; ++e) {
            int ch = ot * 16 + kg * 4 + e;
            float a = acc[ot][e] + obL[ch];
            float g = acc[ot + 8][e] + obL[ch + 128];
            float sg = 1.0f / (1.0f + expf(-g));
            float z = fmaf(a, sg, hbuf[((size_t)(b * HH + ch)) * LL + lpos]);
            acc[ot][e] = z;
            s += z; qq += z * z;
        }
    }
    s += __shfl_xor(s, 16); qq += __shfl_xor(qq, 16);
    s += __shfl_xor(s, 32); qq += __shfl_xor(qq, 32);
    float mu  = s * (1.0f / 128.0f);
    float var = qq * (1.0f / 128.0f) - mu * mu;
    float rs  = rsqrtf(var + 1e-5f);
    const float* lgL = ln_g + layer * HH;
    const float* lbL = ln_b + layer * HH;
#pragma unroll
    for (int ot = 0; ot < 8; ++ot) {
#pragma unroll
        for (int e = 0; e < 4; ++e) {
            int ch = ot * 16 + kg * 4 + e;
            hbuf[((size_t)(b * HH + ch)) * LL + lpos] = (acc[ot][e] - mu) * rs * lgL[ch] + lbL[ch];
        }
    }
}

// ---------------- mean pool over L ----------------
__global__ __launch_bounds__(64) void k_pool(const float* __restrict__ hbuf, float* __restrict__ pooled) {
    int row = blockIdx.x;                 // B*H
    int t = threadIdx.x;                  // 64
    const float* p = hbuf + (size_t)row * LL;
    float s = 0.0f;
    for (int l = t; l < LL; l += 64) s += p[l];
    s += __shfl_xor(s, 32); s += __shfl_xor(s, 16); s += __shfl_xor(s, 8);
    s += __shfl_xor(s, 4);  s += __shfl_xor(s, 2);  s += __shfl_xor(s, 1);
    if (t == 0) pooled[row] = s * (1.0f / LL);
}

// ---------------- decoder ----------------
__global__ __launch_bounds__(256) void k_dec(const float* __restrict__ pooled, const float* __restrict__ dec_w,
                                             const float* __restrict__ dec_b, float* __restrict__ out) {
    int idx = blockIdx.x * 256 + threadIdx.x;
    if (idx >= BB * DOUTN) return;
    int o = idx % DOUTN;
    int b = idx / DOUTN;
    float s = dec_b[o];
    for (int h = 0; h < HH; ++h) s = fmaf(dec_w[o * HH + h], pooled[b * HH + h], s);
    out[idx] = s;
}

extern "C" void kernel_launch(void* const* d_in, const int* in_sizes, int n_in,
                              void* d_out, int out_size, void* d_ws, size_t ws_size,
                              hipStream_t stream) {
    const float* x          = (const float*)d_in[0];
    const float* enc_w      = (const float*)d_in[1];
    const float* enc_b      = (const float*)d_in[2];
    const float* log_dt     = (const float*)d_in[3];
    const float* C          = (const float*)d_in[4];
    const float* log_A_real = (const float*)d_in[5];
    const float* A_imag     = (const float*)d_in[6];
    const float* D          = (const float*)d_in[7];
    const float* out_w      = (const float*)d_in[8];
    const float* out_b      = (const float*)d_in[9];
    const float* ln_g       = (const float*)d_in[10];
    const float* ln_b       = (const float*)d_in[11];
    const float* dec_w      = (const float*)d_in[12];
    const float* dec_b      = (const float*)d_in[13];
    float* out = (float*)d_out;

    float* hbuf   = (float*)d_ws;                                  // B*H*L fp32 (32 MB)
    float* ybuf   = hbuf + (size_t)BB * HH * LL;                   // B*H*L fp32 (32 MB)
    short* Ahi    = (short*)(ybuf + (size_t)BB * HH * LL);         // 4*16*4*64*8 shorts (256 KB)
    short* Alo    = Ahi + (size_t)NLAYERS * 16 * 4 * 64 * 8;
    float* pooled = (float*)(Alo + (size_t)NLAYERS * 16 * 4 * 64 * 8);

    hipLaunchKernelGGL(k_pack, dim3(64), dim3(256), 0, stream, out_w, Ahi, Alo);
    hipLaunchKernelGGL(k_enc, dim3(BB * HH * LL / 4 / 256), dim3(256), 0, stream, x, enc_w, enc_b, hbuf);
    for (int layer = 0; layer < NLAYERS; ++layer) {
        hipLaunchKernelGGL(k_scan, dim3(BB * HH), dim3(64), 0, stream,
                           hbuf, ybuf, log_dt, C, log_A_real, A_imag, layer);
        hipLaunchKernelGGL(k_conv, dim3(BB * (LL / 64)), dim3(256), 0, stream,
                           hbuf, ybuf, Ahi, Alo, out_b, D, ln_g, ln_b, layer);
    }
    hipLaunchKernelGGL(k_pool, dim3(BB * HH), dim3(64), 0, stream, hbuf, pooled);
    hipLaunchKernelGGL(k_dec, dim3((BB * DOUTN + 255) / 256), dim3(256), 0, stream, pooled, dec_w, dec_b, out);
}

// Round 6
// 598.868 us; speedup vs baseline: 1.3492x; 1.3492x over previous
//
#include <hip/hip_runtime.h>
#include <math.h>

#define BB 16
#define LL 4096
#define HH 128
#define NN2 32
#define NHALF 16
#define CHUNK 128
#define NCHUNK 32
#define NLAYERS 4
#define DOUTN 100
#define TWOH 256

typedef __attribute__((ext_vector_type(8))) short short8;
typedef __attribute__((ext_vector_type(4))) float f32x4;

__device__ __forceinline__ unsigned short f2bf(float f) {
    unsigned int u = __builtin_bit_cast(unsigned int, f);
    unsigned int r = (u + 0x7FFFu + ((u >> 16) & 1u)) >> 16;
    return (unsigned short)r;
}
__device__ __forceinline__ float bf2f(unsigned short s) {
    unsigned int u = ((unsigned int)s) << 16;
    return __builtin_bit_cast(float, u);
}

// ---------------- pack out_w (nl,2H,H) into MFMA A-fragment layout, bf16 hi/lo ----------------
// A-frag for mfma_f32_16x16x32_bf16: lane = m + 16*(k/8), elem = k%8.
__global__ __launch_bounds__(256) void k_pack(const float* __restrict__ out_w,
                                              short* __restrict__ Ahi, short* __restrict__ Alo) {
    int idx = blockIdx.x * 256 + threadIdx.x;          // 4*16*4*64 = 16384
    if (idx >= NLAYERS * 16 * 4 * 64) return;
    int lane = idx & 63;
    int ks   = (idx >> 6) & 3;
    int ot   = (idx >> 8) & 15;
    int layer = idx >> 12;
    int o = ot * 16 + (lane & 15);
    short8 hi, lo;
#pragma unroll
    for (int e = 0; e < 8; ++e) {
        int h = ks * 32 + (lane >> 4) * 8 + e;
        float w = out_w[((size_t)(layer * TWOH + o)) * HH + h];
        unsigned short wh = f2bf(w);
        float res = w - bf2f(wh);
        hi[e] = (short)wh;
        lo[e] = (short)f2bf(res);
    }
    *(short8*)(Ahi + (size_t)idx * 8) = hi;
    *(short8*)(Alo + (size_t)idx * 8) = lo;
}

// ---------------- encoder: h[b,h,l] = x[b,l]*enc_w[h] + enc_b[h] ----------------
__global__ __launch_bounds__(256) void k_enc(const float* __restrict__ x, const float* __restrict__ enc_w,
                                             const float* __restrict__ enc_b, float* __restrict__ hbuf) {
    int idx = blockIdx.x * 256 + threadIdx.x;       // over B*H*L/4
    int l4 = idx & (LL / 4 - 1);
    int h  = (idx / (LL / 4)) & (HH - 1);
    int b  = idx / (LL / 4 * HH);
    float4 xv = ((const float4*)(x + (size_t)b * LL))[l4];
    float w = enc_w[h], bb = enc_b[h];
    float4 o;
    o.x = fmaf(xv.x, w, bb);
    o.y = fmaf(xv.y, w, bb);
    o.z = fmaf(xv.z, w, bb);
    o.w = fmaf(xv.w, w, bb);
    ((float4*)(hbuf + ((size_t)b * HH + h) * LL))[l4] = o;
}

// ---------------- SSM scan, chunk-parallel, 16 modes/lane (unchanged from R4) ----------------
__global__ __launch_bounds__(64, 2) void k_scan(const float* __restrict__ u_, float* __restrict__ y_,
                                                const float* __restrict__ log_dt, const float* __restrict__ Cc,
                                                const float* __restrict__ log_A_real, const float* __restrict__ A_imag,
                                                int layer) {
    int row   = blockIdx.x;                 // b*H + h
    int h     = row & (HH - 1);
    int lane  = threadIdx.x;
    int chunk = lane & 31;
    int half  = lane >> 5;
    const float* urow = u_ + (size_t)row * LL + chunk * CHUNK;
    float*       yrow = y_ + (size_t)row * LL + chunk * CHUNK;

    float dt = expf(log_dt[layer * HH + h]);
    float plr[NHALF], pli[NHALF], pc2r[NHALF], pc2i[NHALF], pmr[NHALF], pmi[NHALF];
#pragma unroll
    for (int n = 0; n < NHALF; ++n) {
        int pidx = (layer * HH + h) * NN2 + half * NHALF + n;
        float Ar  = -expf(log_A_real[pidx]);
        float Ai  = A_imag[pidx];
        float dAr = Ar * dt, dAi = Ai * dt;
        float el  = expf(dAr);
        float lr  = el * cosf(dAi);
        float li  = el * sinf(dAi);
        plr[n] = lr; pli[n] = li;
        float nr  = lr - 1.0f, ni = li;
        float inv = 1.0f / (Ar * Ar + Ai * Ai);
        float gr  = (nr * Ar + ni * Ai) * inv;
        float gi  = (ni * Ar - nr * Ai) * inv;
        float Cre = Cc[pidx * 2], Cim = Cc[pidx * 2 + 1];
        pc2r[n] = 2.0f * (Cre * gr - Cim * gi);
        pc2i[n] = 2.0f * (Cre * gi + Cim * gr);
        float eC = expf(dAr * (float)CHUNK);
        float aC = dAi * (float)CHUNK;
        pmr[n] = eC * cosf(aC);
        pmi[n] = eC * sinf(aC);
    }

    float sr[NHALF], si[NHALF];
#pragma unroll
    for (int n = 0; n < NHALF; ++n) { sr[n] = 0.0f; si[n] = 0.0f; }

    // phase 1: local chunk scan (zero init)
    float4 uv = *(const float4*)(urow);
#pragma unroll 1
    for (int s0 = 0; s0 < CHUNK; s0 += 4) {
        int sn = s0 + 4 < CHUNK ? s0 + 4 : CHUNK - 4;
        float4 uvn = *(const float4*)(urow + sn);
        float us4[4] = {uv.x, uv.y, uv.z, uv.w};
#pragma unroll
        for (int j = 0; j < 4; ++j) {
            float u = us4[j];
#pragma unroll
            for (int n = 0; n < NHALF; ++n) {
                float t   = fmaf(-pli[n], si[n], u);
                float nsi = fmaf(pli[n], sr[n], plr[n] * si[n]);
                sr[n] = fmaf(plr[n], sr[n], t);
                si[n] = nsi;
            }
        }
        uv = uvn;
    }

    // combine: inclusive complex prefix over 32 chunks (per half)
    {
        float mr[NHALF], mi[NHALF];
#pragma unroll
        for (int n = 0; n < NHALF; ++n) { mr[n] = pmr[n]; mi[n] = pmi[n]; }
#pragma unroll
        for (int k = 1; k < NCHUNK; k <<= 1) {
#pragma unroll
            for (int n = 0; n < NHALF; ++n) {
                float vr = __shfl_up(sr[n], k);
                float vi = __shfl_up(si[n], k);
                vr = (chunk >= k) ? vr : 0.0f;
                vi = (chunk >= k) ? vi : 0.0f;
                sr[n] = fmaf(mr[n], vr, fmaf(-mi[n], vi, sr[n]));
                si[n] = fmaf(mr[n], vi, fmaf(mi[n], vr, si[n]));
            }
#pragma unroll
            for (int n = 0; n < NHALF; ++n) {
                float t = fmaf(mr[n], mr[n], -(mi[n] * mi[n]));
                mi[n] = 2.0f * mr[n] * mi[n];
                mr[n] = t;
            }
        }
#pragma unroll
        for (int n = 0; n < NHALF; ++n) {
            float vr = __shfl_up(sr[n], 1);
            float vi = __shfl_up(si[n], 1);
            sr[n] = (chunk >= 1) ? vr : 0.0f;
            si[n] = (chunk >= 1) ? vi : 0.0f;
        }
    }

    // phase 2: re-run with true incoming state, emit y
    uv = *(const float4*)(urow);
#pragma unroll 1
    for (int s0 = 0; s0 < CHUNK; s0 += 4) {
        int sn = s0 + 4 < CHUNK ? s0 + 4 : CHUNK - 4;
        float4 uvn = *(const float4*)(urow + sn);
        float us4[4] = {uv.x, uv.y, uv.z, uv.w};
        float out4[4];
#pragma unroll
        for (int j = 0; j < 4; ++j) {
            float u = us4[j];
            float acc_a = 0.0f, acc_b = 0.0f;
#pragma unroll
            for (int n = 0; n < NHALF; n += 2) {
                {
                    float t   = fmaf(-pli[n], si[n], u);
                    float nsi = fmaf(pli[n], sr[n], plr[n] * si[n]);
                    sr[n] = fmaf(plr[n], sr[n], t);
                    si[n] = nsi;
                    acc_a = fmaf(pc2r[n], sr[n], fmaf(-pc2i[n], si[n], acc_a));
                }
                {
                    int m = n + 1;
                    float t   = fmaf(-pli[m], si[m], u);
                    float nsi = fmaf(pli[m], sr[m], plr[m] * si[m]);
                    sr[m] = fmaf(plr[m], sr[m], t);
                    si[m] = nsi;
                    acc_b = fmaf(pc2r[m], sr[m], fmaf(-pc2i[m], si[m], acc_b));
                }
            }
            out4[j] = acc_a + acc_b;
        }
        out4[0] += __shfl_xor(out4[0], 32);
        out4[1] += __shfl_xor(out4[1], 32);
        out4[2] += __shfl_xor(out4[2], 32);
        out4[3] += __shfl_xor(out4[3], 32);
        if (half == 0) *(float4*)(yrow + s0) = make_float4(out4[0], out4[1], out4[2], out4[3]);
        uv = uvn;
    }
}

// ---------------- conv(1x1 H->2H) via MFMA bf16 hi/lo + GLU + residual + LayerNorm ----------------
// v2: vectorized float4 staging; g packed (bf16hi|bf16lo) u32 in LDS [l][h]
// with 16B-granule XOR swizzle (conflict-free b128 frag reads); residual u
// kept in LDS fp32 [l][h] stride-133 (2-way reads, free). Epilogue residual
// comes from LDS, not global.
__global__ __launch_bounds__(256, 2) void k_conv(float* __restrict__ hbuf, const float* __restrict__ ybuf,
                                                 const short* __restrict__ Ahi, const short* __restrict__ Alo,
                                                 const float* __restrict__ out_b, const float* __restrict__ Dp,
                                                 const float* __restrict__ ln_g, const float* __restrict__ ln_b,
                                                 int layer) {
    __shared__ unsigned gs[64 * 132];   // 33.8 KB: [l][granule-swz(h)] packed bf16 hi|lo
    __shared__ float    us[64 * 133];   // 34.0 KB: [l][h] fp32 residual, stride 133
    int tid = threadIdx.x;
    int blk = blockIdx.x;                 // B * (L/64)
    int b   = blk >> 6;
    int l0  = (blk & 63) << 6;
    const float* Drow = Dp + layer * HH;

    // ---- staging: wave w -> h in [32w, 32w+32); thread -> (h = 32w+8*(t6>>4)+i, l = 4*(t6&15)+j)
    {
        int w  = tid >> 6;
        int t6 = tid & 63;
        int lq = (t6 & 15) * 4;
        int hb = 32 * w + 8 * (t6 >> 4);
#pragma unroll
        for (int i = 0; i < 8; ++i) {
            int h = hb + i;
            float d = Drow[h];
            size_t base = ((size_t)(b * HH + h)) * LL + l0 + lq;
            float4 yv = *(const float4*)(ybuf + base);
            float4 uv = *(const float4*)(hbuf + base);
            float ys[4] = {yv.x, yv.y, yv.z, yv.w};
            float uu[4] = {uv.x, uv.y, uv.z, uv.w};
#pragma unroll
            for (int j = 0; j < 4; ++j) {
                int l = lq + j;
                float t = fmaf(d, uu[j], ys[j]);
                float g = 0.5f * t * (1.0f + erff(t * 0.70710678118654752f));
                unsigned short gh = f2bf(g);
                unsigned short gl = f2bf(g - bf2f(gh));
                gs[l * 132 + ((((h >> 2) ^ (l & 7)) << 2) | (h & 3))] = ((unsigned)gh << 16) | (unsigned)gl;
                us[l * 133 + h] = uu[j];
            }
        }
    }
    __syncthreads();

    // ---- MFMA: wave owns l-window [wave*16, +16); lane -> (n = lane&15, kg = lane>>4)
    int wave = tid >> 6;
    int lane = tid & 63;
    int n    = lane & 15;
    int kg   = lane >> 4;
    int ll2  = wave * 16 + n;             // local l of this lane's B column / D column

    short8 Bhi[4], Blo[4];
#pragma unroll
    for (int ks = 0; ks < 4; ++ks) {
        int G0 = 8 * ks + 2 * kg;
        uint4 w0 = *(const uint4*)&gs[ll2 * 132 + (((G0)     ^ (ll2 & 7)) << 2)];
        uint4 w1 = *(const uint4*)&gs[ll2 * 132 + (((G0 + 1) ^ (ll2 & 7)) << 2)];
        unsigned wv[8] = {w0.x, w0.y, w0.z, w0.w, w1.x, w1.y, w1.z, w1.w};
#pragma unroll
        for (int e = 0; e < 8; ++e) {
            Bhi[ks][e] = (short)(wv[e] >> 16);
            Blo[ks][e] = (short)(wv[e] & 0xFFFFu);
        }
    }

    f32x4 acc[16];
#pragma unroll
    for (int ot = 0; ot < 16; ++ot) acc[ot] = (f32x4)(0.0f);

    const short* Abase_hi = Ahi + ((size_t)(layer * 16) * 4 * 64) * 8;
    const short* Abase_lo = Alo + ((size_t)(layer * 16) * 4 * 64) * 8;
#pragma unroll
    for (int ot = 0; ot < 16; ++ot) {
#pragma unroll
        for (int ks = 0; ks < 4; ++ks) {
            size_t aoff = ((size_t)(ot * 4 + ks) * 64 + lane) * 8;
            short8 ah = *(const short8*)(Abase_hi + aoff);
            short8 al = *(const short8*)(Abase_lo + aoff);
            acc[ot] = __builtin_amdgcn_mfma_f32_16x16x32_bf16(ah, Bhi[ks], acc[ot], 0, 0, 0);
            acc[ot] = __builtin_amdgcn_mfma_f32_16x16x32_bf16(ah, Blo[ks], acc[ot], 0, 0, 0);
            acc[ot] = __builtin_amdgcn_mfma_f32_16x16x32_bf16(al, Bhi[ks], acc[ot], 0, 0, 0);
        }
    }

    // ---- epilogue: bias + GLU + residual(from LDS), LN over 128 ch, store ----
    size_t lpos = (size_t)l0 + ll2;
    const float* obL = out_b + layer * TWOH;
    float s = 0.0f, qq = 0.0f;
#pragma unroll
    for (int ot = 0; ot < 8; ++ot) {
#pragma unroll
        for (int e = 0; e < 4; ++e) {
            int ch = ot * 16 + kg * 4 + e;
            float a = acc[ot][e] + obL[ch];
            float g = acc[ot + 8][e] + obL[ch + 128];
            float sg = 1.0f / (1.0f + expf(-g));
            float z = fmaf(a, sg, us[ll2 * 133 + ch]);
            acc[ot][e] = z;
            s += z; qq += z * z;
        }
    }
    s += __shfl_xor(s, 16); qq += __shfl_xor(qq, 16);
    s += __shfl_xor(s, 32); qq += __shfl_xor(qq, 32);
    float mu  = s * (1.0f / 128.0f);
    float var = qq * (1.0f / 128.0f) - mu * mu;
    float rs  = rsqrtf(var + 1e-5f);
    const float* lgL = ln_g + layer * HH;
    const float* lbL = ln_b + layer * HH;
#pragma unroll
    for (int ot = 0; ot < 8; ++ot) {
#pragma unroll
        for (int e = 0; e < 4; ++e) {
            int ch = ot * 16 + kg * 4 + e;
            hbuf[((size_t)(b * HH + ch)) * LL + lpos] = (acc[ot][e] - mu) * rs * lgL[ch] + lbL[ch];
        }
    }
}

// ---------------- mean pool over L ----------------
__global__ __launch_bounds__(64) void k_pool(const float* __restrict__ hbuf, float* __restrict__ pooled) {
    int row = blockIdx.x;                 // B*H
    int t = threadIdx.x;                  // 64
    const float* p = hbuf + (size_t)row * LL;
    float s = 0.0f;
    for (int l = t; l < LL; l += 64) s += p[l];
    s += __shfl_xor(s, 32); s += __shfl_xor(s, 16); s += __shfl_xor(s, 8);
    s += __shfl_xor(s, 4);  s += __shfl_xor(s, 2);  s += __shfl_xor(s, 1);
    if (t == 0) pooled[row] = s * (1.0f / LL);
}

// ---------------- decoder ----------------
__global__ __launch_bounds__(256) void k_dec(const float* __restrict__ pooled, const float* __restrict__ dec_w,
                                             const float* __restrict__ dec_b, float* __restrict__ out) {
    int idx = blockIdx.x * 256 + threadIdx.x;
    if (idx >= BB * DOUTN) return;
    int o = idx % DOUTN;
    int b = idx / DOUTN;
    float s = dec_b[o];
    for (int h = 0; h < HH; ++h) s = fmaf(dec_w[o * HH + h], pooled[b * HH + h], s);
    out[idx] = s;
}

extern "C" void kernel_launch(void* const* d_in, const int* in_sizes, int n_in,
                              void* d_out, int out_size, void* d_ws, size_t ws_size,
                              hipStream_t stream) {
    const float* x          = (const float*)d_in[0];
    const float* enc_w      = (const float*)d_in[1];
    const float* enc_b      = (const float*)d_in[2];
    const float* log_dt     = (const float*)d_in[3];
    const float* C          = (const float*)d_in[4];
    const float* log_A_real = (const float*)d_in[5];
    const float* A_imag     = (const float*)d_in[6];
    const float* D          = (const float*)d_in[7];
    const float* out_w      = (const float*)d_in[8];
    const float* out_b      = (const float*)d_in[9];
    const float* ln_g       = (const float*)d_in[10];
    const float* ln_b       = (const float*)d_in[11];
    const float* dec_w      = (const float*)d_in[12];
    const float* dec_b      = (const float*)d_in[13];
    float* out = (float*)d_out;

    float* hbuf   = (float*)d_ws;                                  // B*H*L fp32 (32 MB)
    float* ybuf   = hbuf + (size_t)BB * HH * LL;                   // B*H*L fp32 (32 MB)
    short* Ahi    = (short*)(ybuf + (size_t)BB * HH * LL);         // 4*16*4*64*8 shorts (256 KB)
    short* Alo    = Ahi + (size_t)NLAYERS * 16 * 4 * 64 * 8;
    float* pooled = (float*)(Alo + (size_t)NLAYERS * 16 * 4 * 64 * 8);

    hipLaunchKernelGGL(k_pack, dim3(64), dim3(256), 0, stream, out_w, Ahi, Alo);
    hipLaunchKernelGGL(k_enc, dim3(BB * HH * LL / 4 / 256), dim3(256), 0, stream, x, enc_w, enc_b, hbuf);
    for (int layer = 0; layer < NLAYERS; ++layer) {
        hipLaunchKernelGGL(k_scan, dim3(BB * HH), dim3(64), 0, stream,
                           hbuf, ybuf, log_dt, C, log_A_real, A_imag, layer);
        hipLaunchKernelGGL(k_conv, dim3(BB * (LL / 64)), dim3(256), 0, stream,
                           hbuf, ybuf, Ahi, Alo, out_b, D, ln_g, ln_b, layer);
    }
    hipLaunchKernelGGL(k_pool, dim3(BB * HH), dim3(64), 0, stream, hbuf, pooled);
    hipLaunchKernelGGL(k_dec, dim3((BB * DOUTN + 255) / 256), dim3(256), 0, stream, pooled, dec_w, dec_b, out);
}